// Round 19
// baseline (132.536 us; speedup 1.0000x reference)
//
#include <hip/hip_runtime.h>

typedef __attribute__((ext_vector_type(4))) float f32x4;
typedef __attribute__((ext_vector_type(8))) short s16x8;
typedef __attribute__((ext_vector_type(4))) unsigned short u16x4;

__device__ inline unsigned short f2bf(float f) {
  unsigned int u = __builtin_bit_cast(unsigned int, f);
  u += 0x7fff + ((u >> 16) & 1);   // RTNE
  return (unsigned short)(u >> 16);
}
__device__ inline float bf2f(unsigned short u) {
  return __builtin_bit_cast(float, (unsigned int)u << 16);
}

__device__ __forceinline__ void async16(const void* g, void* s) {
  __builtin_amdgcn_global_load_lds(
      (const __attribute__((address_space(1))) unsigned int*)g,
      (__attribute__((address_space(3))) unsigned int*)s, 16, 0, 0);
}

// ---------------- K0: cast weights (transposed) + E only ----------------
__global__ __launch_bounds__(256) void cast_kernel(
    const float* __restrict__ wq, const float* __restrict__ wk, const float* __restrict__ wv,
    const float* __restrict__ wo, const float* __restrict__ pos,
    unsigned short* __restrict__ wqT, unsigned short* __restrict__ wkT,
    unsigned short* __restrict__ wvT, unsigned short* __restrict__ woT,
    unsigned short* __restrict__ ebf) {
  int seg = blockIdx.y;
  int tid = blockIdx.x * blockDim.x + threadIdx.x;
  int stride = gridDim.x * blockDim.x;
  if (seg < 4) {
    const float* src = seg == 0 ? wq : seg == 1 ? wk : seg == 2 ? wv : wo;
    unsigned short* dst = seg == 0 ? wqT : seg == 1 ? wkT : seg == 2 ? wvT : woT;
    for (int i = tid; i < 512 * 128; i += stride) {
      int n = i >> 7, k0 = (i & 127) * 4;
      u16x4 o = {f2bf(src[(k0 + 0) * 512 + n]), f2bf(src[(k0 + 1) * 512 + n]),
                 f2bf(src[(k0 + 2) * 512 + n]), f2bf(src[(k0 + 3) * 512 + n])};
      *(u16x4*)&dst[n * 512 + k0] = o;
    }
  } else {
    for (int i = tid; i < 1024 * 64 / 4; i += stride) {
      f32x4 x = *(const f32x4*)&pos[1024 * 64 + i * 4];
      u16x4 o = {f2bf(x[0]), f2bf(x[1]), f2bf(x[2]), f2bf(x[3])};
      *(u16x4*)&ebf[i * 4] = o;
    }
  }
}

// ---------------- K1: fused cast + q/k/v projections (z = 0,1,2) ----------------
__global__ __launch_bounds__(256, 2) void proj3_kernel(
    const float* __restrict__ qf, const float* __restrict__ kf,
    const float* __restrict__ vf, const unsigned short* __restrict__ wqT,
    const unsigned short* __restrict__ wkT, const unsigned short* __restrict__ wvT,
    const float* __restrict__ wq_b, const float* __restrict__ wk_b,
    const float* __restrict__ wv_b, unsigned short* __restrict__ qhw,
    unsigned short* __restrict__ khw, unsigned short* __restrict__ vhT) {
  __shared__ unsigned short As[128 * 32];
  __shared__ unsigned short Bs[128 * 32];
  int z = blockIdx.z;
  const float* A = z == 0 ? qf : z == 1 ? kf : vf;
  const unsigned short* Bt = z == 0 ? wqT : z == 1 ? wkT : wvT;
  const float* bias = z == 0 ? wq_b : z == 1 ? wk_b : wv_b;
  unsigned short* outp = z == 0 ? qhw : z == 1 ? khw : vhT;
  int r0 = blockIdx.x * 128, c0 = blockIdx.y * 128;
  int tid = threadIdx.x;
  int lane = tid & 63, w = tid >> 6;
  int wr = w >> 1, wc = w & 1;
  int frow = lane & 15, kg = lane >> 4;
  f32x4 acc[4][4] = {};
  for (int k0 = 0; k0 < 512; k0 += 32) {
#pragma unroll
    for (int j = 0; j < 2; ++j) {
      int t = tid + j * 256;
      int row = t >> 2, col = (t & 3) * 8;
      f32x4 a0 = *(const f32x4*)&A[(size_t)(r0 + row) * 512 + k0 + col];
      f32x4 a1 = *(const f32x4*)&A[(size_t)(r0 + row) * 512 + k0 + col + 4];
      u16x4 p0 = {f2bf(a0[0]), f2bf(a0[1]), f2bf(a0[2]), f2bf(a0[3])};
      u16x4 p1 = {f2bf(a1[0]), f2bf(a1[1]), f2bf(a1[2]), f2bf(a1[3])};
      *(u16x4*)&As[row * 32 + col] = p0;
      *(u16x4*)&As[row * 32 + col + 4] = p1;
      *(s16x8*)&Bs[row * 32 + col] = *(const s16x8*)&Bt[(size_t)(c0 + row) * 512 + k0 + col];
    }
    __syncthreads();
    s16x8 af[4], bfr[4];
#pragma unroll
    for (int mi = 0; mi < 4; ++mi) af[mi] = *(s16x8*)&As[(wr * 64 + mi * 16 + frow) * 32 + kg * 8];
#pragma unroll
    for (int ni = 0; ni < 4; ++ni) bfr[ni] = *(s16x8*)&Bs[(wc * 64 + ni * 16 + frow) * 32 + kg * 8];
#pragma unroll
    for (int mi = 0; mi < 4; ++mi)
#pragma unroll
      for (int ni = 0; ni < 4; ++ni)
        acc[mi][ni] = __builtin_amdgcn_mfma_f32_16x16x32_bf16(af[mi], bfr[ni], acc[mi][ni], 0, 0, 0);
    __syncthreads();
  }
#pragma unroll
  for (int ni = 0; ni < 4; ++ni) {
    int gc = c0 + wc * 64 + ni * 16 + frow;
    float bi = bias[gc];
#pragma unroll
    for (int mi = 0; mi < 4; ++mi) {
#pragma unroll
      for (int reg = 0; reg < 4; ++reg) {
        int gr = r0 + wr * 64 + mi * 16 + kg * 4 + reg;
        float val = acc[mi][ni][reg] + bi;
        if (z != 2) {   // [nh][l][d]
          outp[(size_t)((gr >> 10) * 8 + (gc >> 6)) * 65536 +
               (size_t)(gr & 1023) * 64 + (gc & 63)] = f2bf(val);
        } else {        // vh transposed: [nh][d][l]
          outp[(size_t)((gr >> 10) * 8 + (gc >> 6)) * 65536 +
               (size_t)(gc & 63) * 1024 + (gr & 1023)] = f2bf(val);
        }
      }
    }
  }
}

// ---------------- K3: final output GEMM (fp32 out, bf16 A) ----------------
__global__ __launch_bounds__(256, 2) void gemm_out_kernel(
    const unsigned short* __restrict__ A, const unsigned short* __restrict__ Bt,
    const float* __restrict__ bias, float* __restrict__ outp) {
  __shared__ unsigned short As[128 * 32];
  __shared__ unsigned short Bs[128 * 32];
  int r0 = blockIdx.x * 128, c0 = blockIdx.y * 128;
  int tid = threadIdx.x;
  int lane = tid & 63, w = tid >> 6;
  int wr = w >> 1, wc = w & 1;
  int frow = lane & 15, kg = lane >> 4;
  f32x4 acc[4][4] = {};
  for (int k0 = 0; k0 < 512; k0 += 32) {
#pragma unroll
    for (int j = 0; j < 2; ++j) {
      int t = tid + j * 256;
      int row = t >> 2, col = (t & 3) * 8;
      *(s16x8*)&As[row * 32 + col] = *(const s16x8*)&A[(size_t)(r0 + row) * 512 + k0 + col];
      *(s16x8*)&Bs[row * 32 + col] = *(const s16x8*)&Bt[(size_t)(c0 + row) * 512 + k0 + col];
    }
    __syncthreads();
    s16x8 af[4], bfr[4];
#pragma unroll
    for (int mi = 0; mi < 4; ++mi) af[mi] = *(s16x8*)&As[(wr * 64 + mi * 16 + frow) * 32 + kg * 8];
#pragma unroll
    for (int ni = 0; ni < 4; ++ni) bfr[ni] = *(s16x8*)&Bs[(wc * 64 + ni * 16 + frow) * 32 + kg * 8];
#pragma unroll
    for (int mi = 0; mi < 4; ++mi)
#pragma unroll
      for (int ni = 0; ni < 4; ++ni)
        acc[mi][ni] = __builtin_amdgcn_mfma_f32_16x16x32_bf16(af[mi], bfr[ni], acc[mi][ni], 0, 0, 0);
    __syncthreads();
  }
#pragma unroll
  for (int ni = 0; ni < 4; ++ni) {
    int gc = c0 + wc * 64 + ni * 16 + frow;
    float bi = bias[gc];
#pragma unroll
    for (int mi = 0; mi < 4; ++mi)
#pragma unroll
      for (int reg = 0; reg < 4; ++reg) {
        int gr = r0 + wr * 64 + mi * 16 + kg * 4 + reg;
        outp[(size_t)gr * 512 + gc] = acc[mi][ni][reg] + bi;
      }
  }
}

// ---------------- K2: relative attention (QBLK=32, 16 waves, barriered pipeline) ----------------
// 1024 blocks (8 XCD x 4 heads x 32 l-tiles) x 1024 threads, 1 block/CU
// (108 KB LDS), 4 rounds of DOUBLE-size blocks: staging + per-block overhead
// amortized 2x per output row vs R18. Per-thread state kept at R10's profile
// (qf 8 + lg[8] 32 + temps) to fit the 1024-thread 64-VGPR cap (R15-R17
// empirical). Staging is not wave-self-contained -> verified T3/T4 pattern:
// counted per-wave vmcnt + raw s_barrier pairs; DMA spans barriers; stage of
// chunk c+2 issued only after the barrier that ends reads of its buffer.
// Wave roles: rg = w>>3 (q-row group of 16), js/ms = w&7 or (w>>1)&3.
__global__ __launch_bounds__(1024, 1) void attn_kernel(
    const unsigned short* __restrict__ qh, const unsigned short* __restrict__ kh,
    const unsigned short* __restrict__ vhT, const unsigned short* __restrict__ ebf,
    const float* __restrict__ mask, float* __restrict__ attn_out,
    unsigned short* __restrict__ ctx) {
  __shared__ unsigned short S[32 * 1024];      // 64 KB: qe, then P
  __shared__ unsigned short KV[2][8192];       // 2 x 16 KB stage buffers
  __shared__ float redmax[16][16], redsum[16][16];
  __shared__ float ctxred[8][16][16];          // 8 KB PV mh-reduce
  int fid = blockIdx.x;
  int nh = ((fid & 7) << 2) | ((fid >> 3) & 3);   // heads pinned to XCD
  int ltile = fid >> 5;                            // 0..31
  int l0 = ltile << 5;
  int tid = threadIdx.x;
  int lane = tid & 63, w = tid >> 6;           // w in 0..15
  int rg = w >> 3, js = w & 7;
  int frow = lane & 15, kg = lane >> 4;
  int qrow = rg * 16 + frow;                   // 0..31

  auto sp = [&](int r, int c) -> unsigned short* {
    int byte = (r << 11) + (c << 1);
    byte ^= (r & 7) << 4;
    return (unsigned short*)((char*)S + byte);
  };

  // Stage 128-row x 128B chunk (E/K [m][64d]); wave w: rows [w*8, w*8+8).
  auto stageKE = [&](const unsigned short* srcbase, int buf) {
    int rl = w * 8 + (lane >> 3);
    int p = lane & 7;
    async16(srcbase + (size_t)rl * 64 + ((p ^ (rl & 7)) * 8), &KV[buf][w * 512]);
  };
  // Stage V^T chunk ([64d][1024m], cols [c*128,+128)); wave w: d-rows [w*4,+4).
  auto stageV = [&](const unsigned short* vsrc, int c, int buf) {
    int dr = w * 4 + (lane >> 4);
    int p = lane & 15;
    int pp = (p & 8) | ((p ^ (dr & 7)) & 7);
    async16(vsrc + (size_t)dr * 1024 + c * 128 + pp * 8, &KV[buf][w * 512]);
  };
  auto waitv1 = [&]() { asm volatile("s_waitcnt vmcnt(1)" ::: "memory"); };
  auto waitv0 = [&]() { asm volatile("s_waitcnt vmcnt(0)" ::: "memory"); };
  auto bar = [&]() {
    __builtin_amdgcn_s_barrier();
    __builtin_amdgcn_sched_barrier(0);
  };
  auto lgkm0 = [&]() {
    asm volatile("s_waitcnt lgkmcnt(0)" ::: "memory");
    __builtin_amdgcn_sched_barrier(0);
  };

  const unsigned short* qbase = qh + ((size_t)nh * 1024 + l0 + qrow) * 64 + kg * 8;
  s16x8 qf0 = *(const s16x8*)(qbase);
  s16x8 qf1 = *(const s16x8*)(qbase + 32);

  int rx = frow & 7;
  int lq = l0 + qrow;

  // ---- Phase A: qe into S ----
  int cmin = 992 - l0;                         // lowest qe col gathered
  int cstart = cmin >> 7;
  stageKE(ebf + (size_t)cstart * 8192, cstart & 1);
  if (cstart + 1 < 8) stageKE(ebf + (size_t)(cstart + 1) * 8192, (cstart + 1) & 1);
  for (int c = cstart; c < 8; ++c) {
    int buf = c & 1;
    if (c + 1 < 8) waitv1(); else waitv0();
    bar();                                     // chunk c fully in LDS
    int j0 = c * 128 + js * 16;
    if (j0 + 15 >= cmin) {
      const char* base = (const char*)&KV[buf][0] + (js * 16 + frow) * 128;
      s16x8 b0 = *(const s16x8*)(base + ((kg ^ rx) << 4));
      s16x8 b1 = *(const s16x8*)(base + (((4 + kg) ^ rx) << 4));
      f32x4 a = {};
      a = __builtin_amdgcn_mfma_f32_16x16x32_bf16(b0, qf0, a, 0, 0, 0);
      a = __builtin_amdgcn_mfma_f32_16x16x32_bf16(b1, qf1, a, 0, 0, 0);
      u16x4 pk = {f2bf(a[0]), f2bf(a[1]), f2bf(a[2]), f2bf(a[3])};
      *(u16x4*)sp(qrow, j0 + kg * 4) = pk;
    }
    lgkm0();
    bar();                                     // all reads of buf done
    if (c + 2 < 8) stageKE(ebf + (size_t)(c + 2) * 8192, buf);
  }
  const unsigned short* kbase = kh + (size_t)nh * 65536;
  stageKE(kbase, 0);
  stageKE(kbase + 8192, 1);
  __syncthreads();   // qe visible; K chunks 0/1 drained into LDS

  // ---- Phase B: lg = Q.K^T ----
  f32x4 lg[8];
#pragma unroll
  for (int c = 0; c < 8; ++c) {
    int buf = c & 1;
    if (c + 1 < 8) waitv1(); else waitv0();
    bar();
    const char* base = (const char*)&KV[buf][0] + (js * 16 + frow) * 128;
    s16x8 b0 = *(const s16x8*)(base + ((kg ^ rx) << 4));
    s16x8 b1 = *(const s16x8*)(base + (((4 + kg) ^ rx) << 4));
    f32x4 a = {};
    a = __builtin_amdgcn_mfma_f32_16x16x32_bf16(b0, qf0, a, 0, 0, 0);
    a = __builtin_amdgcn_mfma_f32_16x16x32_bf16(b1, qf1, a, 0, 0, 0);
    lg[c] = a;
    lgkm0();
    bar();
    if (c + 2 < 8) stageKE(kbase + (size_t)(c + 2) * 8192, buf);
  }

  // V prefetch chunks 0/1 (drained by the syncthreads inside softmax)
  const unsigned short* vsrc = vhT + (size_t)nh * 65536;
  stageV(vsrc, 0, 0);
  stageV(vsrc, 1, 1);

  // ---- srel gather + scale + mask ----
#pragma unroll
  for (int c = 0; c < 8; ++c) {
    int m0k = c * 128 + js * 16 + kg * 4;
    f32x4 mk = *(const f32x4*)&mask[(size_t)lq * 1024 + m0k];
#pragma unroll
    for (int reg = 0; reg < 4; ++reg) {
      int m = m0k + reg;
      float srel = (m <= lq) ? bf2f(*sp(qrow, 1023 + m - lq)) : 0.f;
      lg[c][reg] = (lg[c][reg] + srel) * 0.125f + mk[reg] * -1e9f;
    }
  }

  // ---- softmax: lane-local + 2 shfls + cross-8-wave (same rg) via LDS ----
  f32x4 vmax = lg[0];
#pragma unroll
  for (int c = 1; c < 8; ++c) {
#pragma unroll
    for (int reg = 0; reg < 4; ++reg) vmax[reg] = fmaxf(vmax[reg], lg[c][reg]);
  }
  float mx = fmaxf(fmaxf(vmax[0], vmax[1]), fmaxf(vmax[2], vmax[3]));
  mx = fmaxf(mx, __shfl_xor(mx, 16));
  mx = fmaxf(mx, __shfl_xor(mx, 32));
  float s = 0.f;
#pragma unroll
  for (int c = 0; c < 8; ++c) {
#pragma unroll
    for (int reg = 0; reg < 4; ++reg) {
      lg[c][reg] = __expf(lg[c][reg] - mx);
      s += lg[c][reg];
    }
  }
  s += __shfl_xor(s, 16);
  s += __shfl_xor(s, 32);
  if (lane < 16) {
    redmax[w][lane] = mx;
    redsum[w][lane] = s;
  }
  __syncthreads();   // stats ready AND all srel gathers of S complete

  float gmax = redmax[rg * 8 + 0][frow];
#pragma unroll
  for (int i = 1; i < 8; ++i) gmax = fmaxf(gmax, redmax[rg * 8 + i][frow]);
  float gsum = 0.f;
#pragma unroll
  for (int i = 0; i < 8; ++i)
    gsum += redsum[rg * 8 + i][frow] * __expf(redmax[rg * 8 + i][frow] - gmax);
  float fac = __expf(mx - gmax) / gsum;

  // write normalized attn (f32x4 direct) + P bf16 into S (over qe)
  size_t arow = ((size_t)nh * 1024 + lq) * 1024;
#pragma unroll
  for (int c = 0; c < 8; ++c) {
    int m0k = c * 128 + js * 16 + kg * 4;
    f32x4 pn;
#pragma unroll
    for (int reg = 0; reg < 4; ++reg) pn[reg] = lg[c][reg] * fac;
    *(f32x4*)&attn_out[arow + m0k] = pn;
    u16x4 pb = {f2bf(pn[0]), f2bf(pn[1]), f2bf(pn[2]), f2bf(pn[3])};
    *(u16x4*)sp(qrow, m0k) = pb;
  }
  __syncthreads();   // P visible; V chunks 0/1 drained

  // ---- Phase D: ctx = P @ V; wave (rg2=w>>3, ms2=(w>>1)&3, mh=w&1) ----
  {
    int ms2 = (w >> 1) & 3, mh = w & 1;
    f32x4 acc = {};
#pragma unroll
    for (int c = 0; c < 8; ++c) {
      int buf = c & 1;
      if (c + 1 < 8) waitv1(); else waitv0();
      bar();
      const char* vbase = (const char*)&KV[buf][0] + (ms2 * 16 + frow) * 256;
#pragma unroll
      for (int ks = 0; ks < 2; ++ks) {
        s16x8 a = *(s16x8*)sp(qrow, c * 128 + mh * 64 + ks * 32 + kg * 8);
        int slot = mh * 8 + ks * 4 + kg;
        int pp = (slot & 8) | ((slot ^ rx) & 7);
        s16x8 b = *(const s16x8*)(vbase + pp * 16);
        acc = __builtin_amdgcn_mfma_f32_16x16x32_bf16(a, b, acc, 0, 0, 0);
      }
      lgkm0();
      bar();
      if (c + 2 < 8) stageV(vsrc, c + 2, buf);
    }
    if (mh == 1) {
#pragma unroll
      for (int reg = 0; reg < 4; ++reg) ctxred[rg * 4 + ms2][kg * 4 + reg][frow] = acc[reg];
    }
    __syncthreads();
    if (mh == 0) {
      int n = nh >> 3, h = nh & 7;
#pragma unroll
      for (int reg = 0; reg < 4; ++reg) {
        float val = acc[reg] + ctxred[rg * 4 + ms2][kg * 4 + reg][frow];
        ctx[((size_t)(n * 1024 + l0 + rg * 16 + kg * 4 + reg)) * 512 +
            h * 64 + ms2 * 16 + frow] = f2bf(val);
      }
    }
  }
}

extern "C" void kernel_launch(void* const* d_in, const int* in_sizes, int n_in,
                              void* d_out, int out_size, void* d_ws, size_t ws_size,
                              hipStream_t stream) {
  const float* v = (const float*)d_in[0];
  const float* k = (const float*)d_in[1];
  const float* q = (const float*)d_in[2];
  const float* mask = (const float*)d_in[3];
  const float* wq_w = (const float*)d_in[4];
  const float* wq_b = (const float*)d_in[5];
  const float* wk_w = (const float*)d_in[6];
  const float* wk_b = (const float*)d_in[7];
  const float* wv_w = (const float*)d_in[8];
  const float* wv_b = (const float*)d_in[9];
  const float* wo_w = (const float*)d_in[10];
  const float* wo_b = (const float*)d_in[11];
  const float* pos = (const float*)d_in[12];

  float* outp = (float*)d_out;
  float* attn_out = outp + (size_t)4 * 1024 * 512;

  char* ws = (char*)d_ws;
  unsigned short* ctx = (unsigned short*)(ws);                              // 4 MB
  unsigned short* wqT = (unsigned short*)(ws + ((size_t)12 << 20));         // 512 KB
  unsigned short* wkT = (unsigned short*)(ws + ((size_t)12 << 20) + (512 << 10));
  unsigned short* wvT = (unsigned short*)(ws + ((size_t)13 << 20));
  unsigned short* woT = (unsigned short*)(ws + ((size_t)13 << 20) + (512 << 10));
  unsigned short* ebf = (unsigned short*)(ws + ((size_t)14 << 20));         // 128 KB
  unsigned short* qhw = (unsigned short*)(ws + ((size_t)16 << 20));         // 4 MB
  unsigned short* khw = (unsigned short*)(ws + ((size_t)20 << 20));         // 4 MB
  unsigned short* vhT = (unsigned short*)(ws + ((size_t)24 << 20));         // 4 MB

  cast_kernel<<<dim3(256, 5), 256, 0, stream>>>(wq_w, wk_w, wv_w, wo_w, pos,
                                                wqT, wkT, wvT, woT, ebf);
  proj3_kernel<<<dim3(32, 4, 3), 256, 0, stream>>>(q, k, v, wqT, wkT, wvT,
                                                   wq_b, wk_b, wv_b, qhw, khw, vhT);
  attn_kernel<<<1024, 1024, 0, stream>>>(qhw, khw, vhT, ebf, mask, attn_out, ctx);
  gemm_out_kernel<<<dim3(32, 4), 256, 0, stream>>>(ctx, woT, wo_b, outp);
}

// Round 20
// 118.747 us; speedup vs baseline: 1.1161x; 1.1161x over previous
//
#include <hip/hip_runtime.h>

typedef __attribute__((ext_vector_type(4))) float f32x4;
typedef __attribute__((ext_vector_type(8))) short s16x8;
typedef __attribute__((ext_vector_type(4))) unsigned short u16x4;

__device__ inline unsigned short f2bf(float f) {
  unsigned int u = __builtin_bit_cast(unsigned int, f);
  u += 0x7fff + ((u >> 16) & 1);   // RTNE
  return (unsigned short)(u >> 16);
}
__device__ inline float bf2f(unsigned short u) {
  return __builtin_bit_cast(float, (unsigned int)u << 16);
}

__device__ __forceinline__ void async16(const void* g, void* s) {
  __builtin_amdgcn_global_load_lds(
      (const __attribute__((address_space(1))) unsigned int*)g,
      (__attribute__((address_space(3))) unsigned int*)s, 16, 0, 0);
}

// ---------------- K0: cast weights (transposed) + E only ----------------
__global__ __launch_bounds__(256) void cast_kernel(
    const float* __restrict__ wq, const float* __restrict__ wk, const float* __restrict__ wv,
    const float* __restrict__ wo, const float* __restrict__ pos,
    unsigned short* __restrict__ wqT, unsigned short* __restrict__ wkT,
    unsigned short* __restrict__ wvT, unsigned short* __restrict__ woT,
    unsigned short* __restrict__ ebf) {
  int seg = blockIdx.y;
  int tid = blockIdx.x * blockDim.x + threadIdx.x;
  int stride = gridDim.x * blockDim.x;
  if (seg < 4) {
    const float* src = seg == 0 ? wq : seg == 1 ? wk : seg == 2 ? wv : wo;
    unsigned short* dst = seg == 0 ? wqT : seg == 1 ? wkT : seg == 2 ? wvT : woT;
    for (int i = tid; i < 512 * 128; i += stride) {
      int n = i >> 7, k0 = (i & 127) * 4;
      u16x4 o = {f2bf(src[(k0 + 0) * 512 + n]), f2bf(src[(k0 + 1) * 512 + n]),
                 f2bf(src[(k0 + 2) * 512 + n]), f2bf(src[(k0 + 3) * 512 + n])};
      *(u16x4*)&dst[n * 512 + k0] = o;
    }
  } else {
    for (int i = tid; i < 1024 * 64 / 4; i += stride) {
      f32x4 x = *(const f32x4*)&pos[1024 * 64 + i * 4];
      u16x4 o = {f2bf(x[0]), f2bf(x[1]), f2bf(x[2]), f2bf(x[3])};
      *(u16x4*)&ebf[i * 4] = o;
    }
  }
}

// ---------------- K1: fused cast + q/k/v projections (z = 0,1,2) ----------------
__global__ __launch_bounds__(256, 2) void proj3_kernel(
    const float* __restrict__ qf, const float* __restrict__ kf,
    const float* __restrict__ vf, const unsigned short* __restrict__ wqT,
    const unsigned short* __restrict__ wkT, const unsigned short* __restrict__ wvT,
    const float* __restrict__ wq_b, const float* __restrict__ wk_b,
    const float* __restrict__ wv_b, unsigned short* __restrict__ qhw,
    unsigned short* __restrict__ khw, unsigned short* __restrict__ vhT) {
  __shared__ unsigned short As[128 * 32];
  __shared__ unsigned short Bs[128 * 32];
  int z = blockIdx.z;
  const float* A = z == 0 ? qf : z == 1 ? kf : vf;
  const unsigned short* Bt = z == 0 ? wqT : z == 1 ? wkT : wvT;
  const float* bias = z == 0 ? wq_b : z == 1 ? wk_b : wv_b;
  unsigned short* outp = z == 0 ? qhw : z == 1 ? khw : vhT;
  int r0 = blockIdx.x * 128, c0 = blockIdx.y * 128;
  int tid = threadIdx.x;
  int lane = tid & 63, w = tid >> 6;
  int wr = w >> 1, wc = w & 1;
  int frow = lane & 15, kg = lane >> 4;
  f32x4 acc[4][4] = {};
  for (int k0 = 0; k0 < 512; k0 += 32) {
#pragma unroll
    for (int j = 0; j < 2; ++j) {
      int t = tid + j * 256;
      int row = t >> 2, col = (t & 3) * 8;
      f32x4 a0 = *(const f32x4*)&A[(size_t)(r0 + row) * 512 + k0 + col];
      f32x4 a1 = *(const f32x4*)&A[(size_t)(r0 + row) * 512 + k0 + col + 4];
      u16x4 p0 = {f2bf(a0[0]), f2bf(a0[1]), f2bf(a0[2]), f2bf(a0[3])};
      u16x4 p1 = {f2bf(a1[0]), f2bf(a1[1]), f2bf(a1[2]), f2bf(a1[3])};
      *(u16x4*)&As[row * 32 + col] = p0;
      *(u16x4*)&As[row * 32 + col + 4] = p1;
      *(s16x8*)&Bs[row * 32 + col] = *(const s16x8*)&Bt[(size_t)(c0 + row) * 512 + k0 + col];
    }
    __syncthreads();
    s16x8 af[4], bfr[4];
#pragma unroll
    for (int mi = 0; mi < 4; ++mi) af[mi] = *(s16x8*)&As[(wr * 64 + mi * 16 + frow) * 32 + kg * 8];
#pragma unroll
    for (int ni = 0; ni < 4; ++ni) bfr[ni] = *(s16x8*)&Bs[(wc * 64 + ni * 16 + frow) * 32 + kg * 8];
#pragma unroll
    for (int mi = 0; mi < 4; ++mi)
#pragma unroll
      for (int ni = 0; ni < 4; ++ni)
        acc[mi][ni] = __builtin_amdgcn_mfma_f32_16x16x32_bf16(af[mi], bfr[ni], acc[mi][ni], 0, 0, 0);
    __syncthreads();
  }
#pragma unroll
  for (int ni = 0; ni < 4; ++ni) {
    int gc = c0 + wc * 64 + ni * 16 + frow;
    float bi = bias[gc];
#pragma unroll
    for (int mi = 0; mi < 4; ++mi) {
#pragma unroll
      for (int reg = 0; reg < 4; ++reg) {
        int gr = r0 + wr * 64 + mi * 16 + kg * 4 + reg;
        float val = acc[mi][ni][reg] + bi;
        if (z != 2) {   // [nh][l][d]
          outp[(size_t)((gr >> 10) * 8 + (gc >> 6)) * 65536 +
               (size_t)(gr & 1023) * 64 + (gc & 63)] = f2bf(val);
        } else {        // vh transposed: [nh][d][l]
          outp[(size_t)((gr >> 10) * 8 + (gc >> 6)) * 65536 +
               (size_t)(gc & 63) * 1024 + (gr & 1023)] = f2bf(val);
        }
      }
    }
  }
}

// ---------------- K3: final output GEMM (fp32 out, bf16 A) ----------------
__global__ __launch_bounds__(256, 2) void gemm_out_kernel(
    const unsigned short* __restrict__ A, const unsigned short* __restrict__ Bt,
    const float* __restrict__ bias, float* __restrict__ outp) {
  __shared__ unsigned short As[128 * 32];
  __shared__ unsigned short Bs[128 * 32];
  int r0 = blockIdx.x * 128, c0 = blockIdx.y * 128;
  int tid = threadIdx.x;
  int lane = tid & 63, w = tid >> 6;
  int wr = w >> 1, wc = w & 1;
  int frow = lane & 15, kg = lane >> 4;
  f32x4 acc[4][4] = {};
  for (int k0 = 0; k0 < 512; k0 += 32) {
#pragma unroll
    for (int j = 0; j < 2; ++j) {
      int t = tid + j * 256;
      int row = t >> 2, col = (t & 3) * 8;
      *(s16x8*)&As[row * 32 + col] = *(const s16x8*)&A[(size_t)(r0 + row) * 512 + k0 + col];
      *(s16x8*)&Bs[row * 32 + col] = *(const s16x8*)&Bt[(size_t)(c0 + row) * 512 + k0 + col];
    }
    __syncthreads();
    s16x8 af[4], bfr[4];
#pragma unroll
    for (int mi = 0; mi < 4; ++mi) af[mi] = *(s16x8*)&As[(wr * 64 + mi * 16 + frow) * 32 + kg * 8];
#pragma unroll
    for (int ni = 0; ni < 4; ++ni) bfr[ni] = *(s16x8*)&Bs[(wc * 64 + ni * 16 + frow) * 32 + kg * 8];
#pragma unroll
    for (int mi = 0; mi < 4; ++mi)
#pragma unroll
      for (int ni = 0; ni < 4; ++ni)
        acc[mi][ni] = __builtin_amdgcn_mfma_f32_16x16x32_bf16(af[mi], bfr[ni], acc[mi][ni], 0, 0, 0);
    __syncthreads();
  }
#pragma unroll
  for (int ni = 0; ni < 4; ++ni) {
    int gc = c0 + wc * 64 + ni * 16 + frow;
    float bi = bias[gc];
#pragma unroll
    for (int mi = 0; mi < 4; ++mi)
#pragma unroll
      for (int reg = 0; reg < 4; ++reg) {
        int gr = r0 + wr * 64 + mi * 16 + kg * 4 + reg;
        outp[(size_t)gr * 512 + gc] = acc[mi][ni][reg] + bi;
      }
  }
}

// ---------------- K2: fused relative attention (R18 final config) ----------------
// 8 waves / 512 threads, one (nh, 16 q-rows) per block, XCD-local head remap
// (nh = 4*(fid&7) + ((fid>>3)&3), l0 = (fid>>5)*16 — heads pinned to XCD).
// Barrier-free per-wave depth-2 DMA pipelines (each wave stages exactly the
// KV region it consumes); counted vmcnt(2); swizzled DMA source + matching
// LDS reads; direct attn_out stores. Measured: attn 83.1 us, FETCH 30.6 MB,
// WRITE 135 MB (= ideal), VGPR 64 no spill, total 118.8 us.
// Exonerated limiters (R4-R19): VALU work, shfls, occupancy/TLP, barriers,
// L2 locality, write path, pipe depth, DMA coalescing, bank conflicts,
// per-block overhead. Remaining floor: serial 5-phase dependent chain.
__global__ __launch_bounds__(512, 2) void attn_kernel(
    const unsigned short* __restrict__ qh, const unsigned short* __restrict__ kh,
    const unsigned short* __restrict__ vhT, const unsigned short* __restrict__ ebf,
    const float* __restrict__ mask, float* __restrict__ attn_out,
    unsigned short* __restrict__ ctx) {
  __shared__ unsigned short S[16 * 1024];      // 32 KB: qe, then P
  __shared__ unsigned short KV[2][8192];       // 2 x 16 KB stage buffers
  __shared__ float redmax[8][16], redsum[8][16];
  __shared__ float ctxred[4][16][16];          // 4 KB PV cross-wave reduce
  int fid = blockIdx.x;
  int nh = ((fid & 7) << 2) | ((fid >> 3) & 3);   // heads pinned to XCD
  int l0 = (fid >> 5) << 4;
  int tid = threadIdx.x;
  int lane = tid & 63, w = tid >> 6;           // w in 0..7
  int frow = lane & 15, kg = lane >> 4;

  auto sp = [&](int r, int c) -> unsigned short* {
    int byte = (r << 11) + (c << 1);
    byte ^= (r & 7) << 4;
    return (unsigned short*)((char*)S + byte);
  };

  // Stage wave w's 16 rows of a 128-row x 128B chunk (E/K: [m][64 d] bf16).
  auto stageKE = [&](const unsigned short* srcbase, int buf) {
#pragma unroll
    for (int i = 0; i < 2; ++i) {
      int u = i * 64 + lane;                   // 0..127
      int row = u >> 3, p = u & 7;             // row 0..15 local, 8x16B parts
      async16(srcbase + (size_t)(w * 16 + row) * 64 + ((p ^ (row & 7)) * 8),
              &KV[buf][w * 1024 + i * 512]);
    }
  };
  // Stage wave w's V^T sub-chunk: d-rows [dg*16,+16) x cols [mh*512+c*64,+64).
  auto stageV = [&](const unsigned short* vsrc, int c, int buf) {
    int mh = w >> 2, dg = w & 3;
#pragma unroll
    for (int i = 0; i < 2; ++i) {
      int u = i * 64 + lane;
      int row = u >> 3, p = u & 7;
      async16(vsrc + (size_t)(dg * 16 + row) * 1024 + mh * 512 + c * 64 + ((p ^ (row & 7)) * 8),
              &KV[buf][w * 1024 + i * 512]);
    }
  };

  // Q fragments (B-operand): row = frow, k = kg*8 + j, two K-halves
  const unsigned short* qbase = qh + ((size_t)nh * 1024 + l0 + frow) * 64 + kg * 8;
  s16x8 qf0 = *(const s16x8*)(qbase);
  s16x8 qf1 = *(const s16x8*)(qbase + 32);

  // ---- Phase A: qe[q][j] = Q[q]·E[j] into S (chunks >= cstart only) ----
  int cmin = 1008 - l0;
  int cstart = cmin >> 7;
  stageKE(ebf + (size_t)cstart * 8192, cstart & 1);
  if (cstart + 1 < 8) stageKE(ebf + (size_t)(cstart + 1) * 8192, (cstart + 1) & 1);
  for (int c = cstart; c < 8; ++c) {
    int buf = c & 1;
    if (c + 1 < 8) { asm volatile("s_waitcnt vmcnt(2)" ::: "memory"); }
    else           { asm volatile("s_waitcnt vmcnt(0)" ::: "memory"); }
    __builtin_amdgcn_sched_barrier(0);
    int j0 = c * 128 + w * 16;                 // wave-uniform tile
    if (j0 + 15 >= cmin) {
      const char* base = (const char*)&KV[buf][0] + w * 2048 + frow * 128;
      s16x8 b0 = *(const s16x8*)(base + ((kg ^ (frow & 7)) << 4));
      s16x8 b1 = *(const s16x8*)(base + (((4 + kg) ^ (frow & 7)) << 4));
      f32x4 a = {};
      a = __builtin_amdgcn_mfma_f32_16x16x32_bf16(b0, qf0, a, 0, 0, 0);
      a = __builtin_amdgcn_mfma_f32_16x16x32_bf16(b1, qf1, a, 0, 0, 0);
      u16x4 pk = {f2bf(a[0]), f2bf(a[1]), f2bf(a[2]), f2bf(a[3])};
      *(u16x4*)sp(frow, j0 + kg * 4) = pk;
    }
    asm volatile("s_waitcnt lgkmcnt(0)" ::: "memory");
    __builtin_amdgcn_sched_barrier(0);
    if (c + 2 < 8) stageKE(ebf + (size_t)(c + 2) * 8192, buf);
  }
  // prefetch K chunks 0/1 before the barrier (barrier drains them anyway)
  const unsigned short* kbase = kh + (size_t)nh * 65536;
  stageKE(kbase, 0);
  stageKE(kbase + 8192, 1);
  __syncthreads();   // qe visible to all waves

  // ---- Phase B: lg = Q·K^T, 1 m-tile per wave per chunk ----
  f32x4 lg[8];
#pragma unroll
  for (int c = 0; c < 8; ++c) {
    int buf = c & 1;
    if (c + 1 < 8) { asm volatile("s_waitcnt vmcnt(2)" ::: "memory"); }
    else           { asm volatile("s_waitcnt vmcnt(0)" ::: "memory"); }
    __builtin_amdgcn_sched_barrier(0);
    const char* base = (const char*)&KV[buf][0] + w * 2048 + frow * 128;
    s16x8 b0 = *(const s16x8*)(base + ((kg ^ (frow & 7)) << 4));
    s16x8 b1 = *(const s16x8*)(base + (((4 + kg) ^ (frow & 7)) << 4));
    f32x4 a = {};
    a = __builtin_amdgcn_mfma_f32_16x16x32_bf16(b0, qf0, a, 0, 0, 0);
    a = __builtin_amdgcn_mfma_f32_16x16x32_bf16(b1, qf1, a, 0, 0, 0);
    lg[c] = a;
    asm volatile("s_waitcnt lgkmcnt(0)" ::: "memory");
    __builtin_amdgcn_sched_barrier(0);
    if (c + 2 < 8) stageKE(kbase + (size_t)(c + 2) * 8192, buf);
  }

  // ---- srel gather + scale + mask (lane's row lq fixed) ----
  int lq = l0 + frow;
#pragma unroll
  for (int c = 0; c < 8; ++c) {
    int m0k = c * 128 + w * 16 + kg * 4;
    f32x4 mk = *(const f32x4*)&mask[(size_t)lq * 1024 + m0k];
#pragma unroll
    for (int reg = 0; reg < 4; ++reg) {
      int m = m0k + reg;
      float srel = (m <= lq) ? bf2f(*sp(frow, 1023 + m - lq)) : 0.f;
      lg[c][reg] = (lg[c][reg] + srel) * 0.125f + mk[reg] * -1e9f;
    }
  }

  // ---- softmax: lane-local (32 vals) + 2 shfls + cross-8-wave via LDS ----
  f32x4 vmax = lg[0];
#pragma unroll
  for (int c = 1; c < 8; ++c) {
#pragma unroll
    for (int reg = 0; reg < 4; ++reg) vmax[reg] = fmaxf(vmax[reg], lg[c][reg]);
  }
  float mx = fmaxf(fmaxf(vmax[0], vmax[1]), fmaxf(vmax[2], vmax[3]));
  mx = fmaxf(mx, __shfl_xor(mx, 16));
  mx = fmaxf(mx, __shfl_xor(mx, 32));
  float s = 0.f;
#pragma unroll
  for (int c = 0; c < 8; ++c) {
#pragma unroll
    for (int reg = 0; reg < 4; ++reg) {
      lg[c][reg] = __expf(lg[c][reg] - mx);
      s += lg[c][reg];
    }
  }
  s += __shfl_xor(s, 16);
  s += __shfl_xor(s, 32);
  if (lane < 16) {
    redmax[w][lane] = mx;
    redsum[w][lane] = s;
  }
  __syncthreads();

  float gmax = redmax[0][frow];
#pragma unroll
  for (int wv = 1; wv < 8; ++wv) gmax = fmaxf(gmax, redmax[wv][frow]);
  float gsum = 0.f;
#pragma unroll
  for (int wv = 0; wv < 8; ++wv) gsum += redsum[wv][frow] * __expf(redmax[wv][frow] - gmax);
  float fac = __expf(mx - gmax) / gsum;

  // write normalized attn (f32x4 direct) + P bf16 (b64) into S
  size_t arow = ((size_t)nh * 1024 + lq) * 1024;
#pragma unroll
  for (int c = 0; c < 8; ++c) {
    int m0k = c * 128 + w * 16 + kg * 4;
    f32x4 pn;
#pragma unroll
    for (int reg = 0; reg < 4; ++reg) pn[reg] = lg[c][reg] * fac;
    *(f32x4*)&attn_out[arow + m0k] = pn;
    u16x4 pb = {f2bf(pn[0]), f2bf(pn[1]), f2bf(pn[2]), f2bf(pn[3])};
    *(u16x4*)sp(frow, m0k) = pb;
  }
  __syncthreads();   // P visible to all waves

  // ---- Phase D: ctx = P @ V; m-half x d-quarter split + LDS reduce ----
  {
    const unsigned short* vsrc = vhT + (size_t)nh * 65536;
    stageV(vsrc, 0, 0);
    stageV(vsrc, 1, 1);
    int mh = w >> 2, dg = w & 3;
    f32x4 acc = {};
#pragma unroll
    for (int c = 0; c < 8; ++c) {
      int buf = c & 1;
      if (c + 1 < 8) { asm volatile("s_waitcnt vmcnt(2)" ::: "memory"); }
      else           { asm volatile("s_waitcnt vmcnt(0)" ::: "memory"); }
      __builtin_amdgcn_sched_barrier(0);
      const char* vbase = (const char*)&KV[buf][0] + w * 2048 + frow * 128;
#pragma unroll
      for (int ks = 0; ks < 2; ++ks) {
        s16x8 a = *(s16x8*)sp(frow, mh * 512 + c * 64 + ks * 32 + kg * 8);
        s16x8 b = *(const s16x8*)(vbase + (((ks * 4 + kg) ^ (frow & 7)) << 4));
        acc = __builtin_amdgcn_mfma_f32_16x16x32_bf16(a, b, acc, 0, 0, 0);
      }
      asm volatile("s_waitcnt lgkmcnt(0)" ::: "memory");
      __builtin_amdgcn_sched_barrier(0);
      if (c + 2 < 8) stageV(vsrc, c + 2, buf);
    }
    if (w >= 4) {
#pragma unroll
      for (int reg = 0; reg < 4; ++reg) ctxred[dg][kg * 4 + reg][frow] = acc[reg];
    }
    __syncthreads();
    if (w < 4) {
      int n = nh >> 3, h = nh & 7;
#pragma unroll
      for (int reg = 0; reg < 4; ++reg) {
        float val = acc[reg] + ctxred[dg][kg * 4 + reg][frow];
        ctx[((size_t)(n * 1024 + l0 + kg * 4 + reg)) * 512 + h * 64 + dg * 16 + frow] =
            f2bf(val);
      }
    }
  }
}

extern "C" void kernel_launch(void* const* d_in, const int* in_sizes, int n_in,
                              void* d_out, int out_size, void* d_ws, size_t ws_size,
                              hipStream_t stream) {
  const float* v = (const float*)d_in[0];
  const float* k = (const float*)d_in[1];
  const float* q = (const float*)d_in[2];
  const float* mask = (const float*)d_in[3];
  const float* wq_w = (const float*)d_in[4];
  const float* wq_b = (const float*)d_in[5];
  const float* wk_w = (const float*)d_in[6];
  const float* wk_b = (const float*)d_in[7];
  const float* wv_w = (const float*)d_in[8];
  const float* wv_b = (const float*)d_in[9];
  const float* wo_w = (const float*)d_in[10];
  const float* wo_b = (const float*)d_in[11];
  const float* pos = (const float*)d_in[12];

  float* outp = (float*)d_out;
  float* attn_out = outp + (size_t)4 * 1024 * 512;

  char* ws = (char*)d_ws;
  unsigned short* ctx = (unsigned short*)(ws);                              // 4 MB
  unsigned short* wqT = (unsigned short*)(ws + ((size_t)12 << 20));         // 512 KB
  unsigned short* wkT = (unsigned short*)(ws + ((size_t)12 << 20) + (512 << 10));
  unsigned short* wvT = (unsigned short*)(ws + ((size_t)13 << 20));
  unsigned short* woT = (unsigned short*)(ws + ((size_t)13 << 20) + (512 << 10));
  unsigned short* ebf = (unsigned short*)(ws + ((size_t)14 << 20));         // 128 KB
  unsigned short* qhw = (unsigned short*)(ws + ((size_t)16 << 20));         // 4 MB
  unsigned short* khw = (unsigned short*)(ws + ((size_t)20 << 20));         // 4 MB
  unsigned short* vhT = (unsigned short*)(ws + ((size_t)24 << 20));         // 4 MB

  cast_kernel<<<dim3(256, 5), 256, 0, stream>>>(wq_w, wk_w, wv_w, wo_w, pos,
                                                wqT, wkT, wvT, woT, ebf);
  proj3_kernel<<<dim3(32, 4, 3), 256, 0, stream>>>(q, k, v, wqT, wkT, wvT,
                                                   wq_b, wk_b, wv_b, qhw, khw, vhT);
  attn_kernel<<<2048, 512, 0, stream>>>(qhw, khw, vhT, ebf, mask, attn_out, ctx);
  gemm_out_kernel<<<dim3(32, 4), 256, 0, stream>>>(ctx, woT, wo_b, outp);
}